// Round 6
// baseline (150.837 us; speedup 1.0000x reference)
//
#include <hip/hip_runtime.h>
#include <hip/hip_bf16.h>

#define T_ 4
#define B_ 4
#define C_ 256
#define H_ 32
#define W_ 32
#define TB_ 16
#define Hh_ 16
#define Wh_ 16
#define INVS2 0.70710678118654752440f
#define EPSBN 1e-5f

// Canonical weight arena offsets (bf16 elements)
#define OFF_HW   0
#define OFF_W1   4096
#define OFF_B1   4352
#define OFF_W2   4368
#define OFF_B2   6672
#define OFF_G1   6688
#define OFF_BE1  7200
#define OFF_G2   7712
#define OFF_BE2  8736
#define OFF_G3   9760
#define OFF_BE3  10016
#define OFF_G4   10272
#define OFF_BE4  10528
#define OFF_G5   10784
#define OFF_BE5  11040
#define W_TOTAL  11296
// stats arena (floats): sums1[1024] | sums2[2048] | sums345[1536]
#define NSUMS    4608

struct WPtrs { const void* p[15]; };

typedef __attribute__((ext_vector_type(8))) short short8;
typedef __attribute__((ext_vector_type(4))) float f32x4;

__device__ inline float bf2f(__hip_bfloat16 v) { return __bfloat162float(v); }
__device__ inline float bfu(unsigned short u) { return __uint_as_float((unsigned)u << 16); }

// ---------------------------------------------------------------------------
// k_prep: self-sniff dtype (fp32 vs bf16), convert weights to bf16 arena,
// zero raw-sums; block 0 publishes flag.
// ---------------------------------------------------------------------------
__global__ __launch_bounds__(256) void k_prep(const unsigned short* __restrict__ xr,
                                              WPtrs wp,
                                              __hip_bfloat16* __restrict__ wc,
                                              float* __restrict__ sums,
                                              int* __restrict__ flag) {
    int tid = threadIdx.x;
    int cnt = 0;
    for (int i = tid; i < 2048; i += 256) {
        int e = (xr[i] >> 7) & 0xFF;
        if (e >= 134) cnt++;
    }
    for (int o = 1; o < 64; o <<= 1) cnt += __shfl_xor(cnt, o, 64);
    __shared__ int sh[4];
    if ((tid & 63) == 0) sh[tid >> 6] = cnt;
    __syncthreads();
    int f = (sh[0] + sh[1] + sh[2] + sh[3] >= 32) ? 1 : 0;
    if (blockIdx.x == 0 && tid == 0) *flag = f;

    const int sizes[15] = {4096, 256, 16, 2304, 16, 512, 512, 1024, 1024,
                           256, 256, 256, 256, 256, 256};
    int i = blockIdx.x * 256 + tid;
    if (i < W_TOTAL) {
        int seg = 0, off = 0;
        while (i >= off + sizes[seg]) { off += sizes[seg]; seg++; }
        int j = i - off;
        float v = f ? ((const float*)wp.p[seg])[j]
                    : bf2f(((const __hip_bfloat16*)wp.p[seg])[j]);
        wc[i] = __float2bfloat16(v);
    }
    if (i < NSUMS) sums[i] = 0.f;
}

// ---------------------------------------------------------------------------
// Fused LIF + Haar-W stats. Planar coalesced uchar2 spikes + BN1 raw sums.
// (Haar-W codes are recomputed downstream directly from the spike pairs.)
// ---------------------------------------------------------------------------
__global__ __launch_bounds__(256) void k_lifhaar(const void* __restrict__ x_,
                                                 const int* __restrict__ flag,
                                                 unsigned char* __restrict__ s,
                                                 float* __restrict__ sums1) {
    int bid = blockIdx.x;                      // 2048 = b(4) * c(256) * half(2)
    int tid = threadIdx.x;
    int half = bid & 1;
    int c = (bid >> 1) & 255;
    int b = bid >> 9;
    int wp = tid & 15;
    int hl = tid >> 4;
    int h = half * 16 + hl;
    int f = *flag;
    const float* xf = (const float*)x_;
    const unsigned int* xb = (const unsigned int*)x_;
    int n = ((b * 256 + c) * 32 + h) * 32 + 2 * wp;

    float v0 = 0.f, v1 = 0.f;
    float aL = 0.f, qL = 0.f, aH = 0.f, qH = 0.f;
    #pragma unroll
    for (int t = 0; t < T_; ++t) {
        size_t idx = (size_t)t * 1048576 + n;
        float x0, x1;
        if (f) {
            float2 xx = *(const float2*)(xf + idx);
            x0 = xx.x; x1 = xx.y;
        } else {
            unsigned int u = xb[idx >> 1];
            x0 = __uint_as_float(u << 16);
            x1 = __uint_as_float(u & 0xffff0000u);
        }
        v0 += (x0 - v0) * 0.5f;
        v1 += (x1 - v1) * 0.5f;
        float s0 = (v0 >= 1.f) ? 1.f : 0.f;
        float s1 = (v1 >= 1.f) ? 1.f : 0.f;
        v0 *= (1.f - s0);
        v1 *= (1.f - s1);
        int tb = t * 4 + b;
        ((uchar2*)s)[(size_t)(tb * 256 + c) * 512 + h * 16 + wp] =
            make_uchar2((unsigned char)s0, (unsigned char)s1);
        float cl = s0 + s1, ch = s0 - s1;
        aL += cl; qL += cl * cl; aH += ch; qH += ch * ch;
    }
    for (int o = 1; o < 64; o <<= 1) {
        aL += __shfl_xor(aL, o, 64); qL += __shfl_xor(qL, o, 64);
        aH += __shfl_xor(aH, o, 64); qH += __shfl_xor(qH, o, 64);
    }
    __shared__ float part[4][4];
    int lane = tid & 63, wv = tid >> 6;
    if (lane == 0) {
        part[wv][0] = aL; part[wv][1] = qL; part[wv][2] = aH; part[wv][3] = qH;
    }
    __syncthreads();
    if (tid < 4) {
        float tot = part[0][tid] + part[1][tid] + part[2][tid] + part[3][tid];
        const int offs[4] = {0, 512, 256, 768};
        atomicAdd(&sums1[offs[tid] + c], tot);
    }
}

// ---------------------------------------------------------------------------
// stage2: BN1-apply + Haar-H + gates -> l2 bf16; BN2 raw sums.
// Reads spike pairs directly from global (no LDS staging).
// ---------------------------------------------------------------------------
__global__ __launch_bounds__(256) void k_stage2(const unsigned char* __restrict__ s,
                                                const float* __restrict__ sums1,
                                                const __hip_bfloat16* __restrict__ wc,
                                                float* __restrict__ stats,
                                                __hip_bfloat16* __restrict__ l2) {
    int blk = blockIdx.x;                 // TB*C = 4096
    int c = blk & 255;
    int tb = blk >> 8;
    int tid = threadIdx.x;
    int lane = tid & 63, wv = tid >> 6;

    const float nrm = 1.f / 8192.f;
    float mL = sums1[c] * INVS2 * nrm;
    float vL = fmaxf(sums1[512 + c] * 0.5f * nrm - mL * mL, 0.f);
    float sL = bf2f(wc[OFF_G1 + c]) * rsqrtf(vL + EPSBN);
    float tL = bf2f(wc[OFF_BE1 + c]) - mL * sL;
    float mH = sums1[256 + c] * INVS2 * nrm;
    float vH = fmaxf(sums1[768 + c] * 0.5f * nrm - mH * mH, 0.f);
    float sH = bf2f(wc[OFF_G1 + 256 + c]) * rsqrtf(vH + EPSBN);
    float tH = bf2f(wc[OFF_BE1 + 256 + c]) - mH * sH;
    float slo = sL * INVS2, shi = sH * INVS2;

    int w = tid & 15, v = tid >> 4;
    const uchar2* sp = (const uchar2*)(s + ((size_t)(tb * 256 + c)) * 1024);
    uchar2 pa = sp[(2 * v) * 16 + w];
    uchar2 pb = sp[(2 * v + 1) * 16 + w];
    float lt = (float)(pa.x + pa.y) * slo + tL;
    float lb = (float)(pb.x + pb.y) * slo + tL;
    float ht = (float)((int)pa.x - (int)pa.y) * shi + tH;
    float hb = (float)((int)pb.x - (int)pb.y) * shi + tH;

    float zLL = (lt + lb) * INVS2;
    float zHL = (lt - lb) * INVS2;
    float zLH = (ht + hb) * INVS2;
    float zHH = (ht - hb) * INVS2;
    zLL = (fabsf(zLL) - 0.5f >= 0.f) ? zLL : 0.f;
    zHL = (fabsf(zHL) - 0.5f >= 0.f) ? zHL : 0.f;
    zLH = (fabsf(zLH) - 0.5f >= 0.f) ? zLH : 0.f;
    zHH = (fabsf(zHH) - 0.5f >= 0.f) ? zHH : 0.f;

    float r0 = zLL, r1 = zHL, r2 = zLH, r3 = zHH;
    float q0 = zLL * zLL, q1 = zHL * zHL, q2 = zLH * zLH, q3 = zHH * zHH;
    for (int o = 1; o < 64; o <<= 1) {
        r0 += __shfl_xor(r0, o, 64); r1 += __shfl_xor(r1, o, 64);
        r2 += __shfl_xor(r2, o, 64); r3 += __shfl_xor(r3, o, 64);
        q0 += __shfl_xor(q0, o, 64); q1 += __shfl_xor(q1, o, 64);
        q2 += __shfl_xor(q2, o, 64); q3 += __shfl_xor(q3, o, 64);
    }
    __shared__ float part[4][8];
    if (lane == 0) {
        part[wv][0] = r0; part[wv][1] = r1; part[wv][2] = r2; part[wv][3] = r3;
        part[wv][4] = q0; part[wv][5] = q1; part[wv][6] = q2; part[wv][7] = q3;
    }
    __syncthreads();
    float S0 = part[0][0] + part[1][0] + part[2][0] + part[3][0];
    float S1 = part[0][1] + part[1][1] + part[2][1] + part[3][1];
    float S2 = part[0][2] + part[1][2] + part[2][2] + part[3][2];
    float S3 = part[0][3] + part[1][3] + part[2][3] + part[3][3];
    float Q0 = part[0][4] + part[1][4] + part[2][4] + part[3][4];
    float Q1 = part[0][5] + part[1][5] + part[2][5] + part[3][5];
    float Q2 = part[0][6] + part[1][6] + part[2][6] + part[3][6];
    float Q3 = part[0][7] + part[1][7] + part[2][7] + part[3][7];
    float fLL = (Q0 * (1.f / 256.f) > 0.01f) ? 1.f : 0.f;
    float fHL = (Q1 * (1.f / 256.f) > 0.02f) ? 1.f : 0.f;
    float fLH = (Q2 * (1.f / 256.f) > 0.02f) ? 1.f : 0.f;
    float fHH = (Q3 * (1.f / 256.f) > 0.05f) ? 1.f : 0.f;

    float* sums2 = stats + 1024;
    if (tid < 8) {
        const int cho[8] = {0, 1024, 256, 1280, 512, 1536, 768, 1792};
        const float vals[8] = {fLL * S0, fLL * Q0, fHL * S1, fHL * Q1,
                               fLH * S2, fLH * Q2, fHH * S3, fHH * Q3};
        atomicAdd(&sums2[cho[tid] + c], vals[tid]);
    }

    size_t ob = (((size_t)tb * 1024) + c) * 256 + tid;
    l2[ob]               = __float2bfloat16(zLL * fLL);
    l2[ob + 256u * 256u] = __float2bfloat16(zHL * fHL);
    l2[ob + 512u * 256u] = __float2bfloat16(zLH * fLH);
    l2[ob + 768u * 256u] = __float2bfloat16(zHH * fHH);
}

// ---------------------------------------------------------------------------
// k_convmix: bids [0,256) = conv role (MFMA implicit GEMM, LDS channel-last
// spikes, BN4/5 sums); bids [256,512) = mixinv role (BN2-apply + block
// matmul + inverse Haar -> rec, BN3 sums). Both only need lifhaar/stage2
// outputs; packing them fills the machine (512 blocks) in one dispatch.
// ---------------------------------------------------------------------------
struct SharedU {
    union {
        struct {
            short lo[1025 * 8];            // channel-last bf16, d 0..7 (+zero row)
            short hi[1025 * 8];            // d 8..15
            unsigned short w2s[2304];      // [k][d*9+tap]
            unsigned short w1s[256];       // [k][d]
            unsigned short bs[32];         // B1 | B2
            float parts[4][4][16];         // [wv][g][r*4+which]
        } cv;
        struct {
            float wt[4][16][16];           // [q][d][k]
            float bsc[64], bsh[64];
            float parts2[4][32];
        } mi;
    };
};

__global__ __launch_bounds__(256) void k_convmix(const unsigned char* __restrict__ s,
                                                 const __hip_bfloat16* __restrict__ l2,
                                                 const __hip_bfloat16* __restrict__ wc,
                                                 float* __restrict__ stats,
                                                 __hip_bfloat16* __restrict__ rec,
                                                 __hip_bfloat16* __restrict__ c1,
                                                 __hip_bfloat16* __restrict__ c2) {
    __shared__ SharedU sm;
    int bid = blockIdx.x;
    int tid = threadIdx.x;
    int lane = tid & 63, wv = tid >> 6;

    if (bid < 256) {
        // ------------------------------ conv role ------------------------------
        int img = bid;
        const unsigned short* wr = (const unsigned short*)wc;
        for (int i = tid; i < 2304; i += 256) sm.cv.w2s[i] = wr[OFF_W2 + i];
        sm.cv.w1s[tid] = wr[OFF_W1 + tid];
        if (tid < 16) { sm.cv.bs[tid] = wr[OFF_B1 + tid]; sm.cv.bs[16 + tid] = wr[OFF_B2 + tid]; }
        if (tid < 8) {
            ((unsigned int*)sm.cv.lo)[4096 + (tid & 3)] = 0;
            ((unsigned int*)sm.cv.hi)[4096 + (tid & 3)] = 0;
        }
        {
            const unsigned int* sp = (const unsigned int*)(s + (size_t)img * 16384);
            int d2 = tid >> 5;
            int pg = tid & 31;
            unsigned int* dst = (unsigned int*)((d2 < 4) ? sm.cv.lo : sm.cv.hi);
            int dl = d2 & 3;
            #pragma unroll
            for (int p = 0; p < 8; ++p) {
                int base = p * 32 + pg;
                unsigned int u0 = sp[d2 * 512 + base];
                unsigned int u1 = sp[d2 * 512 + 256 + base];
                #pragma unroll
                for (int jj = 0; jj < 4; ++jj) {
                    int j = (jj + pg) & 3;
                    unsigned int b0 = (u0 >> (8 * j)) & 255u;
                    unsigned int b1 = (u1 >> (8 * j)) & 255u;
                    unsigned int val = (b0 ? 0x3F80u : 0u) | ((b1 ? 0x3F80u : 0u) << 16);
                    int pix = p * 128 + pg * 4 + j;
                    dst[pix * 4 + dl] = val;
                }
            }
        }
        __syncthreads();

        int m = lane & 15;
        int g = lane >> 4;
        const int tapA[5] = {0, 2, 4, 6, 8};
        const int tapB[5] = {1, 3, 5, 7, 8};

        short8 afr[5], a1f;
        #pragma unroll
        for (int p = 0; p < 5; ++p) {
            int tap = (g < 2) ? tapA[p] : tapB[p];
            short8 av;
            #pragma unroll
            for (int j = 0; j < 8; ++j) {
                int d = (g & 1) * 8 + j;
                unsigned short w = sm.cv.w2s[m * 144 + d * 9 + tap];
                if (p == 4 && g >= 2) w = 0;
                av[j] = (short)w;
            }
            afr[p] = av;
        }
        #pragma unroll
        for (int j = 0; j < 8; ++j) {
            int d = (g & 1) * 8 + j;
            a1f[j] = (g < 2) ? (short)sm.cv.w1s[m * 16 + d] : (short)0;
        }
        float bias1[4], bias2[4];
        #pragma unroll
        for (int r = 0; r < 4; ++r) {
            bias1[r] = bfu(sm.cv.bs[g * 4 + r]);
            bias2[r] = bfu(sm.cv.bs[16 + g * 4 + r]);
        }

        __hip_bfloat16* o1 = c1 + (size_t)img * 16384;
        __hip_bfloat16* o2 = c2 + (size_t)img * 16384;
        const short* bsrc = (g & 1) ? sm.cv.hi : sm.cv.lo;

        float cs1[4] = {0, 0, 0, 0}, cq1[4] = {0, 0, 0, 0};
        float cs2[4] = {0, 0, 0, 0}, cq2[4] = {0, 0, 0, 0};

        for (int t = wv * 16; t < wv * 16 + 16; ++t) {
            int h = t >> 1;
            int w0 = (t & 1) << 4;
            f32x4 acc2 = {0.f, 0.f, 0.f, 0.f};
            f32x4 acc1 = {0.f, 0.f, 0.f, 0.f};
            #pragma unroll
            for (int p = 0; p < 5; ++p) {
                int tap = (g < 2) ? tapA[p] : tapB[p];
                int row = h + tap / 3 - 1;
                int col = w0 + m + (tap % 3) - 1;
                bool ok = ((unsigned)row < 32u) && ((unsigned)col < 32u);
                int idx = ok ? (row * 32 + col) : 1024;
                short8 bv = *(const short8*)&bsrc[idx * 8];
                acc2 = __builtin_amdgcn_mfma_f32_16x16x32_bf16(afr[p], bv, acc2, 0, 0, 0);
                if (p == 2)
                    acc1 = __builtin_amdgcn_mfma_f32_16x16x32_bf16(a1f, bv, acc1, 0, 0, 0);
            }
            int pix = h * 32 + w0 + m;
            #pragma unroll
            for (int r = 0; r < 4; ++r) {
                int k = g * 4 + r;
                float y1 = acc1[r] + bias1[r];
                float y2 = acc2[r] + bias2[r];
                o1[(size_t)k * 1024 + pix] = __float2bfloat16(y1);
                o2[(size_t)k * 1024 + pix] = __float2bfloat16(y2);
                cs1[r] += y1; cq1[r] += y1 * y1;
                cs2[r] += y2; cq2[r] += y2 * y2;
            }
        }
        #pragma unroll
        for (int o = 1; o < 16; o <<= 1) {
            #pragma unroll
            for (int r = 0; r < 4; ++r) {
                cs1[r] += __shfl_xor(cs1[r], o, 64);
                cq1[r] += __shfl_xor(cq1[r], o, 64);
                cs2[r] += __shfl_xor(cs2[r], o, 64);
                cq2[r] += __shfl_xor(cq2[r], o, 64);
            }
        }
        if (m == 0) {
            #pragma unroll
            for (int r = 0; r < 4; ++r) {
                sm.cv.parts[wv][g][r * 4 + 0] = cs1[r];
                sm.cv.parts[wv][g][r * 4 + 1] = cq1[r];
                sm.cv.parts[wv][g][r * 4 + 2] = cs2[r];
                sm.cv.parts[wv][g][r * 4 + 3] = cq2[r];
            }
        }
        __syncthreads();
        if (tid < 64) {
            int gg = tid >> 4, r = (tid >> 2) & 3, which = tid & 3;
            float tot = sm.cv.parts[0][gg][r * 4 + which] + sm.cv.parts[1][gg][r * 4 + which]
                      + sm.cv.parts[2][gg][r * 4 + which] + sm.cv.parts[3][gg][r * 4 + which];
            int ch = (img & 15) * 16 + gg * 4 + r;
            const int base[4] = {3584, 3840, 4096, 4352};
            atomicAdd(&stats[base[which] + ch], tot);
        }
    } else {
        // ------------------------------ mixinv role ------------------------------
        int mb = bid - 256;                   // 256 = tb(16) * cg(16)
        int cg = mb & 15;
        int tb = mb >> 4;
        const float* sums2 = stats + 1024;

        for (int i = tid; i < 1024; i += 256) {
            int q = i >> 8, rem = i & 255, d = rem >> 4, k = rem & 15;
            int nb = q * 4 + (cg >> 2);
            sm.mi.wt[q][d][k] = bf2f(wc[OFF_HW + nb * 256 + d * 16 + k]);
        }
        if (tid < 64) {
            int q = tid >> 4, d = tid & 15;
            int ch = q * 256 + cg * 16 + d;
            float m = sums2[ch] * (1.f / 4096.f);
            float var = fmaxf(sums2[1024 + ch] * (1.f / 4096.f) - m * m, 0.f);
            float sc = bf2f(wc[OFF_G2 + ch]) * rsqrtf(var + EPSBN);
            sm.mi.bsc[tid] = sc;
            sm.mi.bsh[tid] = bf2f(wc[OFF_BE2 + ch]) - m * sc;
        }
        __syncthreads();

        float h[4][16];
        #pragma unroll
        for (int q = 0; q < 4; ++q)
            #pragma unroll
            for (int k = 0; k < 16; ++k) h[q][k] = 0.f;

        int p = tid;
        #pragma unroll
        for (int q = 0; q < 4; ++q) {
            const __hip_bfloat16* base =
                l2 + ((size_t)tb * 1024 + q * 256 + cg * 16) * 256 + p;
            #pragma unroll
            for (int d = 0; d < 16; ++d) {
                float xv = bf2f(base[d * 256]) * sm.mi.bsc[q * 16 + d] + sm.mi.bsh[q * 16 + d];
                #pragma unroll
                for (int k = 0; k < 16; ++k)
                    h[q][k] = fmaf(xv, sm.mi.wt[q][d][k], h[q][k]);
            }
        }

        int uh = tid >> 4, uw = tid & 15;
        __hip_bfloat16* ob = rec + ((size_t)tb * 256 + cg * 16) * 1024;
        float sk[16], qk[16];
        #pragma unroll
        for (int k = 0; k < 16; ++k) {
            float LL = h[0][k], HL = h[1][k], LH = h[2][k], HH = h[3][k];
            float v00 = 0.5f * (LL + HL + LH + HH);
            float v01 = 0.5f * (LL + HL - LH - HH);
            float v10 = 0.5f * (LL - HL + LH - HH);
            float v11 = 0.5f * (LL - HL - LH + HH);
            __hip_bfloat162 top, bot;
            top.x = __float2bfloat16(v00); top.y = __float2bfloat16(v01);
            bot.x = __float2bfloat16(v10); bot.y = __float2bfloat16(v11);
            *(__hip_bfloat162*)(ob + (size_t)k * 1024 + (2 * uh) * 32 + 2 * uw) = top;
            *(__hip_bfloat162*)(ob + (size_t)k * 1024 + (2 * uh + 1) * 32 + 2 * uw) = bot;
            sk[k] = v00 + v01 + v10 + v11;
            qk[k] = v00 * v00 + v01 * v01 + v10 * v10 + v11 * v11;
        }
        for (int o = 1; o < 64; o <<= 1) {
            #pragma unroll
            for (int k = 0; k < 16; ++k) {
                sk[k] += __shfl_xor(sk[k], o, 64);
                qk[k] += __shfl_xor(qk[k], o, 64);
            }
        }
        if (lane == 0) {
            #pragma unroll
            for (int k = 0; k < 16; ++k) {
                sm.mi.parts2[wv][k * 2]     = sk[k];
                sm.mi.parts2[wv][k * 2 + 1] = qk[k];
            }
        }
        __syncthreads();
        if (tid < 32) {
            int k = tid >> 1, which = tid & 1;
            float tot = sm.mi.parts2[0][tid] + sm.mi.parts2[1][tid]
                      + sm.mi.parts2[2][tid] + sm.mi.parts2[3][tid];
            atomicAdd(&stats[3072 + which * 256 + cg * 16 + k], tot);
        }
    }
}

// ---------------------------------------------------------------------------
// Final combine (8 elems/thread, 16B loads); derives BN3/4/5 coefficients
// from raw sums (channel is block-uniform).
// ---------------------------------------------------------------------------
__global__ __launch_bounds__(256) void k_final(const __hip_bfloat16* __restrict__ rec,
                                               const __hip_bfloat16* __restrict__ c1,
                                               const __hip_bfloat16* __restrict__ c2,
                                               const float* __restrict__ stats,
                                               const __hip_bfloat16* __restrict__ wc,
                                               const int* __restrict__ flag,
                                               void* __restrict__ out_) {
    int n8 = blockIdx.x * 256 + threadIdx.x;    // 524,288 groups of 8
    int c = ((n8 * 8) >> 10) & 255;
    const float inv = 1.f / 16384.f;
    float m3 = stats[3072 + c] * inv;
    float v3 = fmaxf(stats[3328 + c] * inv - m3 * m3, 0.f);
    float sc3 = bf2f(wc[OFF_G3 + c]) * rsqrtf(v3 + EPSBN);
    float sh3 = bf2f(wc[OFF_BE3 + c]) - m3 * sc3;
    float m4 = stats[3584 + c] * inv;
    float v4 = fmaxf(stats[3840 + c] * inv - m4 * m4, 0.f);
    float sc4 = bf2f(wc[OFF_G4 + c]) * rsqrtf(v4 + EPSBN);
    float sh4 = bf2f(wc[OFF_BE4 + c]) - m4 * sc4;
    float m5 = stats[4096 + c] * inv;
    float v5 = fmaxf(stats[4352 + c] * inv - m5 * m5, 0.f);
    float sc5 = bf2f(wc[OFF_G5 + c]) * rsqrtf(v5 + EPSBN);
    float sh5 = bf2f(wc[OFF_BE5 + c]) - m5 * sc5;

    short8 r = ((const short8*)rec)[n8];
    short8 a = ((const short8*)c1)[n8];
    short8 b = ((const short8*)c2)[n8];
    float v[8];
    #pragma unroll
    for (int j = 0; j < 8; ++j) {
        v[j] = bfu((unsigned short)r[j]) * sc3 + sh3
             + bfu((unsigned short)a[j]) * sc4 + sh4
             + bfu((unsigned short)b[j]) * sc5 + sh5;
    }
    if (*flag) {
        float4* o = (float4*)out_;
        o[n8 * 2]     = make_float4(v[0], v[1], v[2], v[3]);
        o[n8 * 2 + 1] = make_float4(v[4], v[5], v[6], v[7]);
    } else {
        short8 o;
        #pragma unroll
        for (int j = 0; j < 8; ++j)
            o[j] = (short)__bfloat16_as_ushort(__float2bfloat16(v[j]));
        ((short8*)out_)[n8] = o;
    }
}

// ---------------------------------------------------------------------------
// Workspace map (uses ~40.2 MB; ws is 256 MiB per fill profile):
//   [0,4M):   s (planar uchar2 spikes)
//   [8,16M):  l2      [16,24M): rec     [24,32M): c1     [32,40M): c2
//   [40M..):  weight arena, stats (4608 floats), flag
// ---------------------------------------------------------------------------
extern "C" void kernel_launch(void* const* d_in, const int* in_sizes, int n_in,
                              void* d_out, int out_size, void* d_ws, size_t ws_size,
                              hipStream_t stream) {
    char* ws = (char*)d_ws;
    unsigned char* s_u8  = (unsigned char*)ws;
    __hip_bfloat16* l2   = (__hip_bfloat16*)(ws + ((size_t)8 << 20));
    __hip_bfloat16* rec  = (__hip_bfloat16*)(ws + ((size_t)16 << 20));
    __hip_bfloat16* c1   = (__hip_bfloat16*)(ws + ((size_t)24 << 20));
    __hip_bfloat16* c2   = (__hip_bfloat16*)(ws + ((size_t)32 << 20));
    __hip_bfloat16* wc   = (__hip_bfloat16*)(ws + ((size_t)40 << 20));
    float* stats         = (float*)(ws + ((size_t)40 << 20) + (64 << 10));
    int* flag            = (int*)(ws + ((size_t)40 << 20) + (128 << 10));

    WPtrs wp;
    for (int i = 0; i < 15; ++i) wp.p[i] = d_in[i + 1];

    dim3 blk(256);
    k_prep<<<dim3(45), blk, 0, stream>>>((const unsigned short*)d_in[0], wp, wc, stats, flag);
    k_lifhaar<<<dim3(2048), blk, 0, stream>>>(d_in[0], flag, s_u8, stats);
    k_stage2<<<dim3(4096), blk, 0, stream>>>(s_u8, stats, wc, stats, l2);
    k_convmix<<<dim3(512), blk, 0, stream>>>(s_u8, l2, wc, stats, rec, c1, c2);
    k_final<<<dim3(2048), blk, 0, stream>>>(rec, c1, c2, stats, wc, flag, d_out);
}